// Round 2
// baseline (514.203 us; speedup 1.0000x reference)
//
#include <hip/hip_runtime.h>
#include <hip/hip_bf16.h>

typedef unsigned short u16;
typedef unsigned int u32;
typedef __attribute__((ext_vector_type(8))) short short8;
typedef __attribute__((ext_vector_type(4))) float f32x4;

#define B_   512   // batch (i and j)
#define C_   256   // channel dim (reduction c)
#define HID_ 512   // MLP hidden
#define HW_  256   // h*w (k)

__device__ __forceinline__ u16 f2b(float f) {
    union { float f; u32 i; } v; v.f = f;
    u32 x = v.i;
    u32 r = (x + 0x7fffu + ((x >> 16) & 1u)) >> 16;
    return (u16)r;
}
__device__ __forceinline__ float b2f(u16 u) {
    union { u32 i; float f; } v; v.i = ((u32)u) << 16; return v.f;
}

// async global->LDS, 16 B per lane; LDS dest = wave-uniform base + lane*16
__device__ __forceinline__ void dma16(const u16* g, u16* l) {
    __builtin_amdgcn_global_load_lds(
        (const __attribute__((address_space(1))) u32*)g,
        (__attribute__((address_space(3))) u32*)l, 16, 0, 0);
}

// ---------------------------------------------------------------------------
// K1: pred = (anchor + MLP(anchor)) @ Wc   -> bf16 [512][256]
// 512 threads / 4 rows per block, split reductions.
// ---------------------------------------------------------------------------
__global__ __launch_bounds__(512) void k_mlp(
        const float* __restrict__ anchor, const float* __restrict__ W1,
        const float* __restrict__ b1, const float* __restrict__ W2,
        const float* __restrict__ b2, const float* __restrict__ Wc,
        u16* __restrict__ pred)
{
    const int row0 = blockIdx.x * 4, t = threadIdx.x;   // t in [0,512)
    __shared__ float a_sh[4][C_];
    __shared__ float h_sh[4][HID_];
    __shared__ float part[2][4][C_];
    __shared__ float a2_sh[4][C_];

    {
        const int r = t >> 8, c = t & 255;              // r in {0,1}
        a_sh[r][c]     = anchor[(size_t)(row0 + r) * C_ + c];
        a_sh[r + 2][c] = anchor[(size_t)(row0 + r + 2) * C_ + c];
    }
    __syncthreads();

    // phase 1: hidden col t for all 4 rows
    {
        float h0 = b1[t], h1 = h0, h2 = h0, h3 = h0;
        #pragma unroll 4
        for (int l = 0; l < C_; ++l) {
            float wv = W1[(size_t)l * HID_ + t];
            h0 += a_sh[0][l] * wv; h1 += a_sh[1][l] * wv;
            h2 += a_sh[2][l] * wv; h3 += a_sh[3][l] * wv;
        }
        h_sh[0][t] = fmaxf(h0, 0.f); h_sh[1][t] = fmaxf(h1, 0.f);
        h_sh[2][t] = fmaxf(h2, 0.f); h_sh[3][t] = fmaxf(h3, 0.f);
    }
    __syncthreads();

    // phase 2: a2 col (t&255), hidden split in halves (t>>8)
    {
        const int c = t & 255, hh = t >> 8;
        float s0 = 0.f, s1 = 0.f, s2 = 0.f, s3 = 0.f;
        #pragma unroll 4
        for (int x = 0; x < 256; ++x) {
            const int h = hh * 256 + x;
            float wv = W2[(size_t)h * C_ + c];
            s0 += h_sh[0][h] * wv; s1 += h_sh[1][h] * wv;
            s2 += h_sh[2][h] * wv; s3 += h_sh[3][h] * wv;
        }
        part[hh][0][c] = s0; part[hh][1][c] = s1;
        part[hh][2][c] = s2; part[hh][3][c] = s3;
    }
    __syncthreads();
    if (t < 256) {
        const float bv = b2[t];
        #pragma unroll
        for (int r = 0; r < 4; ++r)
            a2_sh[r][t] = a_sh[r][t] + bv + part[0][r][t] + part[1][r][t];
    }
    __syncthreads();

    // phase 3: pred col (t&255), latent split in halves (t>>8)
    {
        const int c = t & 255, dh = t >> 8;
        float s0 = 0.f, s1 = 0.f, s2 = 0.f, s3 = 0.f;
        #pragma unroll 4
        for (int x = 0; x < 128; ++x) {
            const int d = dh * 128 + x;
            float wv = Wc[(size_t)d * C_ + c];
            s0 += a2_sh[0][d] * wv; s1 += a2_sh[1][d] * wv;
            s2 += a2_sh[2][d] * wv; s3 += a2_sh[3][d] * wv;
        }
        part[dh][0][c] = s0; part[dh][1][c] = s1;
        part[dh][2][c] = s2; part[dh][3][c] = s3;
    }
    __syncthreads();
    if (t < 256) {
        #pragma unroll
        for (int r = 0; r < 4; ++r)
            pred[(size_t)(row0 + r) * C_ + t] = f2b(part[0][r][t] + part[1][r][t]);
    }
}

// ---------------------------------------------------------------------------
// KT: P[k][j][c] (bf16) = positive[j][c][k] (f32)   -- unchanged (verified)
// ---------------------------------------------------------------------------
__global__ __launch_bounds__(256) void k_transpose(
        const float* __restrict__ positive, u16* __restrict__ P)
{
    const int bx = blockIdx.x;
    const int j  = bx >> 2;
    const int k0 = (bx & 3) * 64;
    const int t  = threadIdx.x;

    __shared__ float Tf[64][68];   // [c_local][k_local], pitch 68

    const float* pj = positive + (size_t)j * (C_ * HW_);

    for (int p = 0; p < 4; ++p) {
        const int c0 = p * 64;
        {
            const int kk = t & 15, cr = t >> 4;
            #pragma unroll
            for (int s = 0; s < 4; ++s) {
                const int cl = s * 16 + cr;
                float4 v = *(const float4*)&pj[(size_t)(c0 + cl) * HW_ + k0 + kk * 4];
                *(float4*)&Tf[cl][kk * 4] = v;
            }
        }
        __syncthreads();
        {
            const int kr = t >> 2, cq = t & 3;
            u32 wpk[8];
            #pragma unroll
            for (int y = 0; y < 16; y += 2) {
                u16 lo = f2b(Tf[cq * 16 + y][kr]);
                u16 hi = f2b(Tf[cq * 16 + y + 1][kr]);
                wpk[y >> 1] = (u32)lo | ((u32)hi << 16);
            }
            u16* dst = P + ((size_t)(k0 + kr) * B_ + j) * C_ + c0 + cq * 16;
            ((uint4*)dst)[0] = make_uint4(wpk[0], wpk[1], wpk[2], wpk[3]);
            ((uint4*)dst)[1] = make_uint4(wpk[4], wpk[5], wpk[6], wpk[7]);
        }
        __syncthreads();
    }
}

// ---------------------------------------------------------------------------
// KG: fused GEMM + row-max + subtract.  16 waves (1024 thr), i-tile 128,
// full j = 512 (fused max needs the whole row).
//   - A panel (128x256 bf16 = 64 KB) staged ONCE in LDS, XOR-swizzled.
//     FIX vs r1: each DMA round covers 32 rows (16 waves x 2 rows), so the
//     round stride is 32 rows (r*32*C_ source, r*1024 octs dest). The r1
//     version strided by 16 rows -> rows 80..127 unstaged (poison -> NaN).
//   - B double-buffered in 16 KB granules (256 j-rows x 32 c), XOR-swizzled,
//     counted s_waitcnt vmcnt(1) + raw s_barrier (prefetch never drained).
//   - swizzle applied by pre-swizzling the GLOBAL source address; LDS dest
//     of global_load_lds stays linear (wave-uniform base + lane*16).
//   - bijective XCD mapping: all 4 i-tiles of one k on the same XCD -> the
//     Pk panel is fetched into one L2 once and reused 4x.
// ---------------------------------------------------------------------------
__global__ __launch_bounds__(1024, 4) void k_gemm_fused(
        const u16* __restrict__ P, const u16* __restrict__ pred,
        float* __restrict__ out)
{
    const int b  = blockIdx.x;                 // 1024 blocks
    const int k  = (b & 7) * 32 + (b >> 5);    // same k => same XCD (b%8 const)
    const int i0 = ((b >> 3) & 3) * 128;

    __shared__ u16 Asm[128 * 256];             // 64 KB, row = 512 B, oct-swizzled
    __shared__ u16 Bsm[2][1024 * 8];           // 2 x 16 KB granules
    __shared__ float maxw[128][8];
    __shared__ float maxv[128];

    const int tid  = threadIdx.x;
    const int lane = tid & 63, w = tid >> 6;   // 16 waves
    const int q = lane >> 4, m = lane & 15;
    const int wi = w >> 3, wj = w & 7;         // 2 x 8 wave grid

    const u16* Pk = P + (size_t)k * (B_ * C_);

    // ---- prologue: stage full A panel (4 dma/wave, 32 rows per round) ------
    {
        const int usrc = (tid & 31) ^ ((tid >> 5) & 7);      // inverse swizzle
        const u16* asrc = pred + (size_t)(i0 + (tid >> 5)) * C_ + usrc * 8;
        #pragma unroll
        for (int r = 0; r < 4; ++r)
            dma16(asrc + (size_t)r * 32 * C_,
                  Asm + (size_t)(r * 1024 + w * 64) * 8);
    }
    // ---- B granule source addressing ---------------------------------------
    // granule (ch,h): 256 rows jl, global j = (jl>>5)*64 + h*32 + (jl&31)
    // phys oct p = logical oct ^ ((j>>1)&3); lane fills slot tid.
    const int jr_base = (tid >> 7) * 64 + ((tid >> 2) & 31);
    const int osw     = (tid & 3) ^ ((tid >> 3) & 3);
    const u16* bsrc   = Pk + (size_t)jr_base * C_ + osw * 8;

    // granule 0 (ch=0,h=0)
    dma16(bsrc, Bsm[0] + (size_t)w * 64 * 8);

    // ---- per-lane LDS read bases -------------------------------------------
    const int bq   = q ^ ((m >> 1) & 3);                     // B phys oct
    const int brd0 = ((wj * 32 + m) * 4 + bq) * 8;           // + n*512
    const int ard0 = (wi * 64 + m) * 256;                    // + mt*4096 + xor*8

    union U { uint4 u; short8 v; };
    U af[4];
    f32x4 acc[4][4];
    #pragma unroll
    for (int a = 0; a < 4; ++a)
        #pragma unroll
        for (int bb = 0; bb < 4; ++bb) acc[a][bb] = f32x4{0.f, 0.f, 0.f, 0.f};

    // ---- main loop: 16 granules (8 chunks x 2 j-halves) --------------------
    #pragma unroll
    for (int g = 0; g < 16; ++g) {
        if (g < 15) {
            const int gn = g + 1, chn = gn >> 1, hn = gn & 1;
            dma16(bsrc + (size_t)hn * 32 * C_ + chn * 32,
                  Bsm[gn & 1] + (size_t)w * 64 * 8);
            asm volatile("s_waitcnt vmcnt(1)" ::: "memory");  // granule g landed
        } else {
            asm volatile("s_waitcnt vmcnt(0)" ::: "memory");
        }
        __builtin_amdgcn_s_barrier();
        asm volatile("" ::: "memory");          // no ds_read hoists above barrier

        const int ch = g >> 1, h = g & 1;
        if (h == 0) {                            // A frags for this chunk
            const int x = ((ch * 4 + q) ^ (m & 7)) * 8;
            #pragma unroll
            for (int mt = 0; mt < 4; ++mt)
                af[mt].u = *(const uint4*)&Asm[ard0 + mt * 4096 + x];
        }
        #pragma unroll
        for (int n = 0; n < 2; ++n) {            // nt = 2h + n
            U bf; bf.u = *(const uint4*)&Bsm[g & 1][brd0 + n * 512];
            #pragma unroll
            for (int mt = 0; mt < 4; ++mt)
                acc[mt][2 * h + n] = __builtin_amdgcn_mfma_f32_16x16x32_bf16(
                    af[mt].v, bf.v, acc[mt][2 * h + n], 0, 0, 0);
        }
        asm volatile("" ::: "memory");          // no ds_read sinks below barrier
        __builtin_amdgcn_s_barrier();
    }

    // ---- epilogue: row-max over full j, subtract, store --------------------
    float pm[4][4];
    #pragma unroll
    for (int mt = 0; mt < 4; ++mt)
        #pragma unroll
        for (int r = 0; r < 4; ++r) {
            float v = acc[mt][0][r];
            #pragma unroll
            for (int nt = 1; nt < 4; ++nt) v = fmaxf(v, acc[mt][nt][r]);
            pm[mt][r] = v;
        }
    #pragma unroll
    for (int d = 1; d < 16; d <<= 1) {
        #pragma unroll
        for (int mt = 0; mt < 4; ++mt)
            #pragma unroll
            for (int r = 0; r < 4; ++r)
                pm[mt][r] = fmaxf(pm[mt][r], __shfl_xor(pm[mt][r], d, 64));
    }
    __syncthreads();
    if (m == 0) {
        #pragma unroll
        for (int mt = 0; mt < 4; ++mt)
            #pragma unroll
            for (int r = 0; r < 4; ++r)
                maxw[wi * 64 + mt * 16 + q * 4 + r][wj] = pm[mt][r];
    }
    __syncthreads();
    if (tid < 128) {
        float v = maxw[tid][0];
        #pragma unroll
        for (int x = 1; x < 8; ++x) v = fmaxf(v, maxw[tid][x]);
        maxv[tid] = v;
    }
    __syncthreads();

    #pragma unroll
    for (int mt = 0; mt < 4; ++mt) {
        #pragma unroll
        for (int r = 0; r < 4; ++r) {
            const int il = wi * 64 + mt * 16 + q * 4 + r;
            const float mv = maxv[il];
            float* orow = out + ((size_t)k * B_ + i0 + il) * B_ + wj * 64;
            #pragma unroll
            for (int nt = 0; nt < 4; ++nt)
                orow[nt * 16 + m] = acc[mt][nt][r] - mv;
        }
    }
}

// ---------------------------------------------------------------------------
extern "C" void kernel_launch(void* const* d_in, const int* in_sizes, int n_in,
                              void* d_out, int out_size, void* d_ws, size_t ws_size,
                              hipStream_t stream)
{
    const float* anchor   = (const float*)d_in[0];
    const float* positive = (const float*)d_in[1];
    const float* W1 = (const float*)d_in[2];
    const float* b1 = (const float*)d_in[3];
    const float* W2 = (const float*)d_in[4];
    const float* b2 = (const float*)d_in[5];
    const float* Wc = (const float*)d_in[6];
    float* out = (float*)d_out;

    u16* pred = (u16*)d_ws;                                   // 256 KB
    u16* P    = (u16*)((char*)d_ws + (size_t)B_ * C_ * 2);    // 67 MB [k][j][c] bf16

    k_mlp<<<B_ / 4, 512, 0, stream>>>(anchor, W1, b1, W2, b2, Wc, pred);
    k_transpose<<<B_ * 4, 256, 0, stream>>>(positive, P);
    k_gemm_fused<<<1024, 1024, 0, stream>>>(P, pred, out);
}

// Round 3
// 504.734 us; speedup vs baseline: 1.0188x; 1.0188x over previous
//
#include <hip/hip_runtime.h>
#include <hip/hip_bf16.h>

typedef unsigned short u16;
typedef unsigned int u32;
typedef __attribute__((ext_vector_type(8))) short short8;
typedef __attribute__((ext_vector_type(4))) float f32x4;

#define B_   512   // batch (i and j)
#define C_   256   // channel dim (reduction c)
#define HID_ 512   // MLP hidden
#define HW_  256   // h*w (k)

__device__ __forceinline__ u16 f2b(float f) {
    union { float f; u32 i; } v; v.f = f;
    u32 x = v.i;
    u32 r = (x + 0x7fffu + ((x >> 16) & 1u)) >> 16;
    return (u16)r;
}
__device__ __forceinline__ float b2f(u16 u) {
    union { u32 i; float f; } v; v.i = ((u32)u) << 16; return v.f;
}

// async global->LDS, 16 B per lane; LDS dest = wave-uniform base + lane*16
__device__ __forceinline__ void dma16(const u16* g, u16* l) {
    __builtin_amdgcn_global_load_lds(
        (const __attribute__((address_space(1))) u32*)g,
        (__attribute__((address_space(3))) u32*)l, 16, 0, 0);
}

// ---------------------------------------------------------------------------
// K1: pred = (anchor + MLP(anchor)) @ Wc   -> bf16 [512][256]
// 256 blocks x 2 rows (all CUs busy), 512 threads, split reductions.
// ---------------------------------------------------------------------------
__global__ __launch_bounds__(512) void k_mlp(
        const float* __restrict__ anchor, const float* __restrict__ W1,
        const float* __restrict__ b1, const float* __restrict__ W2,
        const float* __restrict__ b2, const float* __restrict__ Wc,
        u16* __restrict__ pred)
{
    const int row0 = blockIdx.x * 2, t = threadIdx.x;   // t in [0,512)
    __shared__ float a_sh[2][C_];
    __shared__ float h_sh[2][HID_];
    __shared__ float part[2][2][C_];
    __shared__ float a2_sh[2][C_];

    {
        const int r = t >> 8, c = t & 255;              // r in {0,1}
        a_sh[r][c] = anchor[(size_t)(row0 + r) * C_ + c];
    }
    __syncthreads();

    // phase 1: hidden col t for both rows
    {
        float h0 = b1[t], h1 = h0;
        #pragma unroll 4
        for (int l = 0; l < C_; ++l) {
            float wv = W1[(size_t)l * HID_ + t];
            h0 += a_sh[0][l] * wv; h1 += a_sh[1][l] * wv;
        }
        h_sh[0][t] = fmaxf(h0, 0.f); h_sh[1][t] = fmaxf(h1, 0.f);
    }
    __syncthreads();

    // phase 2: a2 col (t&255), hidden split in halves (t>>8)
    {
        const int c = t & 255, hh = t >> 8;
        float s0 = 0.f, s1 = 0.f;
        #pragma unroll 4
        for (int x = 0; x < 256; ++x) {
            const int h = hh * 256 + x;
            float wv = W2[(size_t)h * C_ + c];
            s0 += h_sh[0][h] * wv; s1 += h_sh[1][h] * wv;
        }
        part[hh][0][c] = s0; part[hh][1][c] = s1;
    }
    __syncthreads();
    if (t < 256) {
        const float bv = b2[t];
        a2_sh[0][t] = a_sh[0][t] + bv + part[0][0][t] + part[1][0][t];
        a2_sh[1][t] = a_sh[1][t] + bv + part[0][1][t] + part[1][1][t];
    }
    __syncthreads();

    // phase 3: pred col (t&255), latent split in halves (t>>8)
    {
        const int c = t & 255, dh = t >> 8;
        float s0 = 0.f, s1 = 0.f;
        #pragma unroll 4
        for (int x = 0; x < 128; ++x) {
            const int d = dh * 128 + x;
            float wv = Wc[(size_t)d * C_ + c];
            s0 += a2_sh[0][d] * wv; s1 += a2_sh[1][d] * wv;
        }
        part[dh][0][c] = s0; part[dh][1][c] = s1;
    }
    __syncthreads();
    if (t < 256) {
        pred[(size_t)row0 * C_ + t]       = f2b(part[0][0][t] + part[1][0][t]);
        pred[(size_t)(row0 + 1) * C_ + t] = f2b(part[0][1][t] + part[1][1][t]);
    }
}

// ---------------------------------------------------------------------------
// KT: P[k][j][c] (bf16) = positive[j][c][k] (f32)   -- unchanged (verified)
// ---------------------------------------------------------------------------
__global__ __launch_bounds__(256) void k_transpose(
        const float* __restrict__ positive, u16* __restrict__ P)
{
    const int bx = blockIdx.x;
    const int j  = bx >> 2;
    const int k0 = (bx & 3) * 64;
    const int t  = threadIdx.x;

    __shared__ float Tf[64][68];   // [c_local][k_local], pitch 68

    const float* pj = positive + (size_t)j * (C_ * HW_);

    for (int p = 0; p < 4; ++p) {
        const int c0 = p * 64;
        {
            const int kk = t & 15, cr = t >> 4;
            #pragma unroll
            for (int s = 0; s < 4; ++s) {
                const int cl = s * 16 + cr;
                float4 v = *(const float4*)&pj[(size_t)(c0 + cl) * HW_ + k0 + kk * 4];
                *(float4*)&Tf[cl][kk * 4] = v;
            }
        }
        __syncthreads();
        {
            const int kr = t >> 2, cq = t & 3;
            u32 wpk[8];
            #pragma unroll
            for (int y = 0; y < 16; y += 2) {
                u16 lo = f2b(Tf[cq * 16 + y][kr]);
                u16 hi = f2b(Tf[cq * 16 + y + 1][kr]);
                wpk[y >> 1] = (u32)lo | ((u32)hi << 16);
            }
            u16* dst = P + ((size_t)(k0 + kr) * B_ + j) * C_ + c0 + cq * 16;
            ((uint4*)dst)[0] = make_uint4(wpk[0], wpk[1], wpk[2], wpk[3]);
            ((uint4*)dst)[1] = make_uint4(wpk[4], wpk[5], wpk[6], wpk[7]);
        }
        __syncthreads();
    }
}

// ---------------------------------------------------------------------------
// KG v3: fused GEMM + row-max + subtract.  512 thr / 8 waves (2x4 grid),
// i-tile 64, full j = 512.  LDS = 32K A + 2x16K B + 1.3K = 66.8 KB ->
// 2 blocks/CU (store tail + granule stalls overlap across blocks).
//   - A panel (64x256 bf16) staged once, XOR-swizzled (phys oct = o^(row&7)).
//   - B double-buffered 16 KB granules (256 j x 32 c), 2 DMAs/thread/granule,
//     counted s_waitcnt vmcnt(2); swizzle phys oct = o^((jl>>1)&3) applied by
//     pre-swizzling the global source (LDS dest stays linear).
//   - bijective XCD map: all 8 i-tiles of one k on one XCD (8x256KB=2MB L2).
// ---------------------------------------------------------------------------
__global__ __launch_bounds__(512, 4) void k_gemm_fused(
        const u16* __restrict__ P, const u16* __restrict__ pred,
        float* __restrict__ out)
{
    const int b  = blockIdx.x;                 // 2048 blocks
    const int k  = (b & 7) * 32 + (b >> 6);    // same k => same XCD (b&7 const)
    const int i0 = ((b >> 3) & 7) * 64;

    __shared__ u16 Asm[64 * 256];              // 32 KB
    __shared__ u16 Bsm[2][1024 * 8];           // 2 x 16 KB granules
    __shared__ float maxw[64][4];
    __shared__ float maxv[64];

    const int tid  = threadIdx.x;
    const int lane = tid & 63, w = tid >> 6;   // 8 waves
    const int q = lane >> 4, m = lane & 15;
    const int wi = w >> 2, wj = w & 3;         // 2 x 4 wave grid

    const u16* Pk = P + (size_t)k * (B_ * C_);

    // ---- prologue: stage full A panel (4 rounds x 16 rows) -----------------
    {
        const int usrc = (tid & 31) ^ ((tid >> 5) & 7);      // inverse swizzle
        const u16* asrc = pred + (size_t)(i0 + (tid >> 5)) * C_ + usrc * 8;
        #pragma unroll
        for (int r = 0; r < 4; ++r)
            dma16(asrc + (size_t)r * 16 * C_,
                  Asm + (size_t)(r * 512 + w * 64) * 8);
    }
    // ---- B granule source addressing ---------------------------------------
    // granule (ch,h): rows jl 0..255, j = (jl>>5)*64 + h*32 + (jl&31)
    // thread t fills slots {t, t+512}; slot s: jl=s>>2, physoct=s&3,
    // logical oct = physoct ^ ((jl>>1)&3)  ->  same key for both slots.
    const int jrow0 = (tid >> 7) * 64 + ((tid >> 2) & 31);   // group 0..3
    const int osw   = (tid & 3) ^ ((tid >> 3) & 3);
    const u16* bsrc = Pk + (size_t)jrow0 * C_ + osw * 8;     // slot t
    // slot t+512: group += 4  ->  + 256 rows

    // granule 0 (ch=0,h=0): two DMAs
    dma16(bsrc,                    Bsm[0] + (size_t)(w * 64) * 8);
    dma16(bsrc + (size_t)256 * C_, Bsm[0] + (size_t)(512 + w * 64) * 8);

    // ---- per-lane LDS read bases -------------------------------------------
    const int bq   = q ^ ((m >> 1) & 3);                     // B phys oct
    const int brd0 = 2 * wj * 1024 + m * 32 + bq * 8;        // u16 units
    const int ard0 = (wi * 32 + m) * 256;                    // + mt*4096 + x

    union U { uint4 u; short8 v; };
    U af[2];
    f32x4 acc[2][8];
    #pragma unroll
    for (int a = 0; a < 2; ++a)
        #pragma unroll
        for (int bb = 0; bb < 8; ++bb) acc[a][bb] = f32x4{0.f, 0.f, 0.f, 0.f};

    // ---- main loop: 16 granules (8 chunks x 2 j-halves) --------------------
    #pragma unroll
    for (int g = 0; g < 16; ++g) {
        if (g < 15) {
            const int gn = g + 1, chn = gn >> 1, hn = gn & 1;
            const u16* s = bsrc + (size_t)hn * 32 * C_ + chn * 32;
            dma16(s,                    Bsm[gn & 1] + (size_t)(w * 64) * 8);
            dma16(s + (size_t)256 * C_, Bsm[gn & 1] + (size_t)(512 + w * 64) * 8);
            asm volatile("s_waitcnt vmcnt(2)" ::: "memory");  // granule g landed
        } else {
            asm volatile("s_waitcnt vmcnt(0)" ::: "memory");
        }
        __builtin_amdgcn_s_barrier();
        asm volatile("" ::: "memory");          // no ds_read hoists above barrier

        const int ch = g >> 1, h = g & 1;
        if (h == 0) {                            // A frags for this chunk
            const int x = ((ch * 4 + q) ^ (m & 7)) * 8;
            #pragma unroll
            for (int mt = 0; mt < 2; ++mt)
                af[mt].u = *(const uint4*)&Asm[ard0 + mt * 4096 + x];
        }
        #pragma unroll
        for (int n = 0; n < 4; ++n) {            // nt = (n>>1)*4 + 2h + (n&1)
            const int nt = (n >> 1) * 4 + 2 * h + (n & 1);
            U bf; bf.u = *(const uint4*)&Bsm[g & 1][brd0 + (n >> 1) * 1024 + (n & 1) * 512];
            #pragma unroll
            for (int mt = 0; mt < 2; ++mt)
                acc[mt][nt] = __builtin_amdgcn_mfma_f32_16x16x32_bf16(
                    af[mt].v, bf.v, acc[mt][nt], 0, 0, 0);
        }
        asm volatile("" ::: "memory");          // no ds_read sinks below barrier
        __builtin_amdgcn_s_barrier();
    }

    // ---- epilogue: row-max over full j, subtract, store --------------------
    float pm[2][4];
    #pragma unroll
    for (int mt = 0; mt < 2; ++mt)
        #pragma unroll
        for (int r = 0; r < 4; ++r) {
            float v = acc[mt][0][r];
            #pragma unroll
            for (int nt = 1; nt < 8; ++nt) v = fmaxf(v, acc[mt][nt][r]);
            pm[mt][r] = v;
        }
    #pragma unroll
    for (int d = 1; d < 16; d <<= 1) {
        #pragma unroll
        for (int mt = 0; mt < 2; ++mt)
            #pragma unroll
            for (int r = 0; r < 4; ++r)
                pm[mt][r] = fmaxf(pm[mt][r], __shfl_xor(pm[mt][r], d, 64));
    }
    if (m == 0) {
        #pragma unroll
        for (int mt = 0; mt < 2; ++mt)
            #pragma unroll
            for (int r = 0; r < 4; ++r)
                maxw[wi * 32 + mt * 16 + q * 4 + r][wj] = pm[mt][r];
    }
    __syncthreads();
    if (tid < 64)
        maxv[tid] = fmaxf(fmaxf(maxw[tid][0], maxw[tid][1]),
                          fmaxf(maxw[tid][2], maxw[tid][3]));
    __syncthreads();

    #pragma unroll
    for (int mt = 0; mt < 2; ++mt) {
        #pragma unroll
        for (int r = 0; r < 4; ++r) {
            const int il = wi * 32 + mt * 16 + q * 4 + r;
            const float mv = maxv[il];
            float* orow = out + ((size_t)k * B_ + i0 + il) * B_ + wj * 128;
            #pragma unroll
            for (int nt = 0; nt < 8; ++nt)
                orow[nt * 16 + m] = acc[mt][nt][r] - mv;
        }
    }
}

// ---------------------------------------------------------------------------
extern "C" void kernel_launch(void* const* d_in, const int* in_sizes, int n_in,
                              void* d_out, int out_size, void* d_ws, size_t ws_size,
                              hipStream_t stream)
{
    const float* anchor   = (const float*)d_in[0];
    const float* positive = (const float*)d_in[1];
    const float* W1 = (const float*)d_in[2];
    const float* b1 = (const float*)d_in[3];
    const float* W2 = (const float*)d_in[4];
    const float* b2 = (const float*)d_in[5];
    const float* Wc = (const float*)d_in[6];
    float* out = (float*)d_out;

    u16* pred = (u16*)d_ws;                                   // 256 KB
    u16* P    = (u16*)((char*)d_ws + (size_t)B_ * C_ * 2);    // 67 MB [k][j][c] bf16

    k_mlp<<<B_ / 2, 512, 0, stream>>>(anchor, W1, b1, W2, b2, Wc, pred);
    k_transpose<<<B_ * 4, 256, 0, stream>>>(positive, P);
    k_gemm_fused<<<2048, 512, 0, stream>>>(P, pred, out);
}